// Round 1
// baseline (663.601 us; speedup 1.0000x reference)
//
#include <hip/hip_runtime.h>

typedef float f4v __attribute__((ext_vector_type(4)));

#define NROI 2048
#define NCH  256
#define MAPH 256
#define MAPW 256
#define HWSZ (MAPH*MAPW)
#define FDIM 2304
#define MN   (2048*256)

// ---------------- RoI Align Rotated (LDS-staged) ----------------
#define RCL   16            // channels per chunk
#define RMAXR 24            // max region rows (worst-case rotated span ~21)
#define RMAXC 26            // max region cols
#define RREG  (RCL*(RMAXR*RMAXC+1))

__global__ __launch_bounds__(256) void roi_kernel(
    const float* __restrict__ fm, const float* __restrict__ boxes,
    const int* __restrict__ bidx, float* __restrict__ xout)
{
    const int n = blockIdx.x;
    const int tid = threadIdx.x;

    __shared__ float s_w00[36], s_w01[36], s_w10[36], s_w11[36];
    __shared__ int s_o00[36], s_o01[36], s_o10[36], s_o11[36];
    __shared__ int s_y0[36], s_x0[36], s_y1[36], s_x1[36];
    __shared__ int s_bb[4];
    __shared__ float region[RREG];

    if (tid < 36) {
        float b0 = boxes[n*7+0], b1 = boxes[n*7+1];
        float b4 = boxes[n*7+4], b5 = boxes[n*7+5], b6 = boxes[n*7+6];
        float cx = (b0 + 51.2f) / 0.4f - 0.5f;
        float cy = (b1 + 51.2f) / 0.4f - 0.5f;
        float w  = b5 / 0.4f;
        float h  = b4 / 0.4f;
        float th = -b6;
        float ct = cosf(th), st = sinf(th);
        float binh = h / 3.0f, binw = w / 3.0f;
        int s  = tid;
        int ph = s / 12, pw = (s % 12) / 4, sy = (s % 4) / 2, sx = s & 1;
        float sgy = ((float)sy + 0.5f) * 0.5f;
        float sgx = ((float)sx + 0.5f) * 0.5f;
        float yy  = -h*0.5f + ((float)ph + sgy) * binh;
        float xxl = -w*0.5f + ((float)pw + sgx) * binw;
        float y = yy*ct - xxl*st + cy;
        float x = yy*st + xxl*ct + cx;
        bool valid = (y > -1.0f) && (y < 256.0f) && (x > -1.0f) && (x < 256.0f);
        y = fminf(fmaxf(y, 0.0f), 255.0f);
        x = fminf(fmaxf(x, 0.0f), 255.0f);
        int y0 = (int)floorf(y); if (y0 > 255) y0 = 255;
        int x0 = (int)floorf(x); if (x0 > 255) x0 = 255;
        int y1 = min(y0+1, 255), x1 = min(x0+1, 255);
        float ly = y - (float)y0, lx = x - (float)x0;
        float hy = 1.0f - ly, hx = 1.0f - lx;
        float v = valid ? 0.25f : 0.0f;   // fold the /4 sample mean into weights
        s_w00[s] = hy*hx*v; s_w01[s] = hy*lx*v;
        s_w10[s] = ly*hx*v; s_w11[s] = ly*lx*v;
        s_y0[s]=y0; s_x0[s]=x0; s_y1[s]=y1; s_x1[s]=x1;
    }
    __syncthreads();
    if (tid == 0) {
        int ylo=256, xlo=256, yhi=-1, xhi=-1;
        for (int s2=0;s2<36;s2++){
            ylo = min(ylo, s_y0[s2]); xlo = min(xlo, s_x0[s2]);
            yhi = max(yhi, s_y1[s2]); xhi = max(xhi, s_x1[s2]);
        }
        int rh = yhi - ylo + 1; if (rh > RMAXR) rh = RMAXR;
        int rw = xhi - xlo + 1; if (rw > RMAXC) rw = RMAXC;
        s_bb[0]=ylo; s_bb[1]=xlo; s_bb[2]=rh; s_bb[3]=rw;
    }
    __syncthreads();
    const int ylo = s_bb[0], xlo = s_bb[1], rh = s_bb[2], rw = s_bb[3];
    const int area  = rh * rw;
    const int areap = area | 1;    // odd LDS stride between channel slices
    if (tid < 36) {
        s_o00[tid] = (s_y0[tid]-ylo)*rw + (s_x0[tid]-xlo);
        s_o01[tid] = (s_y0[tid]-ylo)*rw + (s_x1[tid]-xlo);
        s_o10[tid] = (s_y1[tid]-ylo)*rw + (s_x0[tid]-xlo);
        s_o11[tid] = (s_y1[tid]-ylo)*rw + (s_x1[tid]-xlo);
    }
    __syncthreads();
    const int b = bidx[n];
    const float* __restrict__ fb = fm + (size_t)b * NCH * HWSZ + ylo*MAPW + xlo;
    const int total = RCL * area;
    const int cl_c = tid & (RCL-1);
    const int pp   = tid >> 4;
    float* __restrict__ xo = xout + (size_t)n * FDIM;

    for (int c0 = 0; c0 < NCH; c0 += RCL) {
        for (int i = tid; i < total; i += 256) {
            int cl  = i / area;
            int rem = i - cl*area;
            int yy2 = rem / rw;
            int xx2 = rem - yy2*rw;
            region[cl*areap + rem] = fb[(size_t)(c0+cl)*HWSZ + yy2*MAPW + xx2];
        }
        __syncthreads();
        if (pp < 9) {
            const float* rc = region + cl_c*areap;
            float acc = 0.0f;
            const int sBase = pp*4;
            #pragma unroll
            for (int q=0;q<4;q++){
                int s2 = sBase + q;
                acc += s_w00[s2]*rc[s_o00[s2]] + s_w01[s2]*rc[s_o01[s2]]
                     + s_w10[s2]*rc[s_o10[s2]] + s_w11[s2]*rc[s_o11[s2]];
            }
            xo[pp*NCH + c0 + cl_c] = acc;
        }
        __syncthreads();
    }
}

// ---------------- fp32 TN GEMM: C[m][n] = A[m][k] * W[n][k] ----------------
struct Ptrs3 {
    const float* A[3];
    const float* W[3];
    float* C[3];
};

template<bool RELU, bool SPLITK>
__global__ __launch_bounds__(256) void gemm_kernel(Ptrs3 p, int M, int N, int K, int kChunk)
{
    __shared__ float As[32*64];
    __shared__ float Bs[32*64];
    const int z = blockIdx.z;
    const float* A; const float* W; float* C;
    int k0, k1;
    if (SPLITK) {
        A = p.A[0]; W = p.W[0];
        k0 = z * kChunk; k1 = k0 + kChunk;
        C = p.C[0] + (size_t)z * M * N;
    } else {
        A = p.A[z]; W = p.W[z]; C = p.C[z];
        k0 = 0; k1 = K;
    }
    const int tid  = threadIdx.x;
    const int m0   = blockIdx.x * 64, n0 = blockIdx.y * 64;
    const int lrow = tid >> 2;          // 0..63 tile row
    const int lk   = (tid & 3) * 8;     // 0,8,16,24
    const float* Ald = A + (size_t)(m0 + lrow) * K + k0 + lk;
    const float* Wld = W + (size_t)(n0 + lrow) * K + k0 + lk;
    const int ty = tid >> 4, tx = tid & 15;
    float acc[4][4] = {};
    for (int kt = k0; kt < k1; kt += 32) {
        f4v a0 = *(const f4v*)Ald;
        f4v a1 = *(const f4v*)(Ald+4);
        f4v b0 = *(const f4v*)Wld;
        f4v b1 = *(const f4v*)(Wld+4);
        __syncthreads();
        As[(lk+0)*64+lrow]=a0[0]; As[(lk+1)*64+lrow]=a0[1];
        As[(lk+2)*64+lrow]=a0[2]; As[(lk+3)*64+lrow]=a0[3];
        As[(lk+4)*64+lrow]=a1[0]; As[(lk+5)*64+lrow]=a1[1];
        As[(lk+6)*64+lrow]=a1[2]; As[(lk+7)*64+lrow]=a1[3];
        Bs[(lk+0)*64+lrow]=b0[0]; Bs[(lk+1)*64+lrow]=b0[1];
        Bs[(lk+2)*64+lrow]=b0[2]; Bs[(lk+3)*64+lrow]=b0[3];
        Bs[(lk+4)*64+lrow]=b1[0]; Bs[(lk+5)*64+lrow]=b1[1];
        Bs[(lk+6)*64+lrow]=b1[2]; Bs[(lk+7)*64+lrow]=b1[3];
        __syncthreads();
        #pragma unroll 8
        for (int k=0;k<32;k++){
            f4v av = *(const f4v*)&As[k*64 + ty*4];
            f4v bv = *(const f4v*)&Bs[k*64 + tx*4];
            #pragma unroll
            for (int i=0;i<4;i++)
                #pragma unroll
                for (int j=0;j<4;j++)
                    acc[i][j] += av[i]*bv[j];
        }
        Ald += 32; Wld += 32;
    }
    float* Cp = C + (size_t)(m0 + ty*4) * N + n0 + tx*4;
    #pragma unroll
    for (int i=0;i<4;i++){
        f4v r;
        #pragma unroll
        for (int j=0;j<4;j++)
            r[j] = RELU ? fmaxf(acc[i][j], 0.0f) : acc[i][j];
        *(f4v*)(Cp + (size_t)i*N) = r;
    }
}

// ---------------- split-K reduce + relu ----------------
__global__ __launch_bounds__(256) void reduce_relu_kernel(
    const float* __restrict__ pin, float* __restrict__ hout)
{
    int i = blockIdx.x * 256 + threadIdx.x;   // over MN/4 float4s
    const f4v* p4 = (const f4v*)pin;
    f4v a = p4[i];
    a += p4[i + MN/4];
    a += p4[i + 2*(MN/4)];
    a += p4[i + 3*(MN/4)];
    f4v r;
    #pragma unroll
    for (int j=0;j<4;j++) r[j] = fmaxf(a[j], 0.0f);
    ((f4v*)hout)[i] = r;
}

// ---------------- final heads (GEMV, one wave per roi) ----------------
__global__ __launch_bounds__(256) void heads_kernel(
    const float* __restrict__ c2, const float* __restrict__ i2, const float* __restrict__ r2,
    const float* __restrict__ wc3, const float* __restrict__ bc3,
    const float* __restrict__ wi3, const float* __restrict__ bi3,
    const float* __restrict__ wr3, const float* __restrict__ br3,
    float* __restrict__ out)
{
    const int lane = threadIdx.x & 63;
    const int wv   = threadIdx.x >> 6;
    const int n    = blockIdx.x * 4 + wv;
    const float* cr = c2 + (size_t)n*256;
    const float* ir = i2 + (size_t)n*256;
    const float* rr = r2 + (size_t)n*256;
    float vc = 0.0f, vi = 0.0f, vr[7] = {};
    #pragma unroll
    for (int j=0;j<4;j++){
        int k = lane + j*64;
        float cv = cr[k], iv = ir[k], rv = rr[k];
        vc += cv * wc3[k];
        vi += iv * wi3[k];
        #pragma unroll
        for (int t=0;t<7;t++) vr[t] += rv * wr3[t*256 + k];
    }
    #pragma unroll
    for (int off=32; off>0; off>>=1){
        vc += __shfl_down(vc, off, 64);
        vi += __shfl_down(vi, off, 64);
        #pragma unroll
        for (int t=0;t<7;t++) vr[t] += __shfl_down(vr[t], off, 64);
    }
    if (lane == 0) {
        out[n]        = vc + bc3[0];
        out[2048 + n] = vi + bi3[0];
        #pragma unroll
        for (int t=0;t<7;t++) out[4096 + n*7 + t] = vr[t] + br3[t];
    }
}

extern "C" void kernel_launch(void* const* d_in, const int* in_sizes, int n_in,
                              void* d_out, int out_size, void* d_ws, size_t ws_size,
                              hipStream_t stream)
{
    const float* fm    = (const float*)d_in[0];
    const float* boxes = (const float*)d_in[1];
    const int*   bidx  = (const int*)d_in[2];
    const float* w_sh1 = (const float*)d_in[3];
    const float* w_sh2 = (const float*)d_in[4];
    const float* w_c1  = (const float*)d_in[5];
    const float* w_c2  = (const float*)d_in[6];
    const float* w_c3  = (const float*)d_in[7];
    const float* b_c3  = (const float*)d_in[8];
    const float* w_i1  = (const float*)d_in[9];
    const float* w_i2  = (const float*)d_in[10];
    const float* w_i3  = (const float*)d_in[11];
    const float* b_i3  = (const float*)d_in[12];
    const float* w_r1  = (const float*)d_in[13];
    const float* w_r2  = (const float*)d_in[14];
    const float* w_r3  = (const float*)d_in[15];
    const float* b_r3  = (const float*)d_in[16];
    float* out = (float*)d_out;

    // workspace layout (floats):
    //   xbuf  : 2048*2304 = 4,718,592   (dead after GEMM1; branch bufs alias it)
    //   h1    : 524,288
    //   sh    : 524,288
    //   part  : 4*524,288 = 2,097,152   (split-K partials)
    // total 7,864,320 floats = 31.5 MB
    float* ws   = (float*)d_ws;
    float* xbuf = ws;
    float* h1   = xbuf + (size_t)2048*2304;
    float* sh   = h1 + MN;
    float* part = sh + MN;
    float* b1c  = xbuf;             // alias region: 6 x 524288 fits in xbuf
    float* b1i  = b1c + MN;
    float* b1r  = b1i + MN;
    float* b2c  = b1r + MN;
    float* b2i  = b2c + MN;
    float* b2r  = b2i + MN;

    roi_kernel<<<NROI, 256, 0, stream>>>(fm, boxes, bidx, xbuf);

    Ptrs3 g1;
    g1.A[0]=xbuf; g1.A[1]=xbuf; g1.A[2]=xbuf;
    g1.W[0]=w_sh1; g1.W[1]=w_sh1; g1.W[2]=w_sh1;
    g1.C[0]=part; g1.C[1]=part; g1.C[2]=part;
    gemm_kernel<false,true><<<dim3(32,4,4), 256, 0, stream>>>(g1, 2048, 256, 2304, 576);

    reduce_relu_kernel<<<MN/4/256, 256, 0, stream>>>(part, h1);

    Ptrs3 g2;
    g2.A[0]=h1; g2.A[1]=h1; g2.A[2]=h1;
    g2.W[0]=w_sh2; g2.W[1]=w_sh2; g2.W[2]=w_sh2;
    g2.C[0]=sh; g2.C[1]=sh; g2.C[2]=sh;
    gemm_kernel<true,false><<<dim3(32,4,1), 256, 0, stream>>>(g2, 2048, 256, 256, 0);

    Ptrs3 g3;
    g3.A[0]=sh; g3.A[1]=sh; g3.A[2]=sh;
    g3.W[0]=w_c1; g3.W[1]=w_i1; g3.W[2]=w_r1;
    g3.C[0]=b1c; g3.C[1]=b1i; g3.C[2]=b1r;
    gemm_kernel<true,false><<<dim3(32,4,3), 256, 0, stream>>>(g3, 2048, 256, 256, 0);

    Ptrs3 g4;
    g4.A[0]=b1c; g4.A[1]=b1i; g4.A[2]=b1r;
    g4.W[0]=w_c2; g4.W[1]=w_i2; g4.W[2]=w_r2;
    g4.C[0]=b2c; g4.C[1]=b2i; g4.C[2]=b2r;
    gemm_kernel<true,false><<<dim3(32,4,3), 256, 0, stream>>>(g4, 2048, 256, 256, 0);

    heads_kernel<<<NROI/4, 256, 0, stream>>>(b2c, b2i, b2r,
                                             w_c3, b_c3, w_i3, b_i3, w_r3, b_r3, out);
}

// Round 2
// 636.672 us; speedup vs baseline: 1.0423x; 1.0423x over previous
//
#include <hip/hip_runtime.h>

typedef float f4v __attribute__((ext_vector_type(4)));

#define NROI 2048
#define NCH  256
#define MAPH 256
#define MAPW 256
#define HWSZ (MAPH*MAPW)
#define FDIM 2304
#define MN   (2048*256)

// ---------------- geometry precompute: one wave per roi ----------------
// geo layout per roi (stride 296 dwords):
//  [0]=ylo [1]=xlo [2]=area [3]=rw [4]=magic [5]=batch  [6,7]=pad
//  [8+s]=w00 [44+s]=w01 [80+s]=w10 [116+s]=w11  (float bits)
//  [152+s]=o00 [188+s]=o01 [224+s]=o10 [260+s]=o11
#define GSTR 296

__global__ __launch_bounds__(256) void geo_kernel(
    const float* __restrict__ boxes, const int* __restrict__ bidx,
    int* __restrict__ geo)
{
    const int lane = threadIdx.x & 63;
    const int n = blockIdx.x * 4 + (threadIdx.x >> 6);

    int y0 = 255, x0 = 255, y1 = 0, x1 = 0;
    float w00 = 0.f, w01 = 0.f, w10 = 0.f, w11 = 0.f;
    if (lane < 36) {
        float b0 = boxes[n*7+0], b1 = boxes[n*7+1];
        float b4 = boxes[n*7+4], b5 = boxes[n*7+5], b6 = boxes[n*7+6];
        float cx = (b0 + 51.2f) / 0.4f - 0.5f;
        float cy = (b1 + 51.2f) / 0.4f - 0.5f;
        float w  = b5 / 0.4f;
        float h  = b4 / 0.4f;
        float th = -b6;
        float ct = cosf(th), st = sinf(th);
        float binh = h / 3.0f, binw = w / 3.0f;
        int s  = lane;
        int ph = s / 12, pw = (s % 12) / 4, sy = (s % 4) / 2, sx = s & 1;
        float sgy = ((float)sy + 0.5f) * 0.5f;
        float sgx = ((float)sx + 0.5f) * 0.5f;
        float yy  = -h*0.5f + ((float)ph + sgy) * binh;
        float xxl = -w*0.5f + ((float)pw + sgx) * binw;
        float y = yy*ct - xxl*st + cy;
        float x = yy*st + xxl*ct + cx;
        bool valid = (y > -1.0f) && (y < 256.0f) && (x > -1.0f) && (x < 256.0f);
        y = fminf(fmaxf(y, 0.0f), 255.0f);
        x = fminf(fmaxf(x, 0.0f), 255.0f);
        y0 = (int)floorf(y); if (y0 > 255) y0 = 255;
        x0 = (int)floorf(x); if (x0 > 255) x0 = 255;
        y1 = min(y0+1, 255); x1 = min(x0+1, 255);
        float ly = y - (float)y0, lx = x - (float)x0;
        float hy = 1.0f - ly, hx = 1.0f - lx;
        float v = valid ? 0.25f : 0.0f;
        w00 = hy*hx*v; w01 = hy*lx*v; w10 = ly*hx*v; w11 = ly*lx*v;
    }
    int ylo = y0, xlo = x0, yhi = y1, xhi = x1;
    #pragma unroll
    for (int off = 32; off; off >>= 1) {
        ylo = min(ylo, __shfl_xor(ylo, off));
        xlo = min(xlo, __shfl_xor(xlo, off));
        yhi = max(yhi, __shfl_xor(yhi, off));
        xhi = max(xhi, __shfl_xor(xhi, off));
    }
    const int rw = xhi - xlo + 1;          // provably <= 24
    const int rh = yhi - ylo + 1;
    int* g = geo + (size_t)n * GSTR;
    if (lane == 0) {
        g[0] = ylo; g[1] = xlo; g[2] = rh * rw; g[3] = rw;
        g[4] = (int)((1u << 22) / (unsigned)rw + 1u);   // exact for idx<576, rw<=24
        g[5] = bidx[n];
    }
    if (lane < 36) {
        g[8   + lane] = __float_as_int(w00);
        g[44  + lane] = __float_as_int(w01);
        g[80  + lane] = __float_as_int(w10);
        g[116 + lane] = __float_as_int(w11);
        g[152 + lane] = (y0 - ylo)*rw + (x0 - xlo);
        g[188 + lane] = (y0 - ylo)*rw + (x1 - xlo);
        g[224 + lane] = (y1 - ylo)*rw + (x0 - xlo);
        g[260 + lane] = (y1 - ylo)*rw + (x1 - xlo);
    }
}

// ---------------- RoI Align main: grid (roi, chunk), 8 ch/chunk ----------------
#define RCL  8
#define RMAX 24
#define RSTR (RMAX*RMAX + 1)   // 577, odd stride between channel slices

__global__ __launch_bounds__(256, 8) void roi_kernel(
    const float* __restrict__ fm, const int* __restrict__ geo,
    float* __restrict__ xout)
{
    const int n   = blockIdx.x;
    const int c0  = blockIdx.y * RCL;
    const int tid = threadIdx.x;

    __shared__ int   sg[GSTR];
    __shared__ float region[RCL * RSTR];

    for (int i = tid; i < GSTR; i += 256) sg[i] = geo[(size_t)n * GSTR + i];
    __syncthreads();

    const int ylo = sg[0], xlo = sg[1], area = sg[2], rw = sg[3];
    const unsigned mg = (unsigned)sg[4];
    const int b = sg[5];

    int  goff[3];
    bool gv[3];
    #pragma unroll
    for (int j = 0; j < 3; j++) {
        int idx = tid + j*256;
        gv[j] = idx < area;
        unsigned yy = ((unsigned)idx * mg) >> 22;
        int xx = idx - (int)yy * rw;
        goff[j] = (int)yy * MAPW + xx;
    }
    const float* __restrict__ fbc =
        fm + ((size_t)b * NCH + c0) * HWSZ + ylo * MAPW + xlo;

    #pragma unroll
    for (int cl = 0; cl < RCL; cl++) {
        #pragma unroll
        for (int j = 0; j < 3; j++)
            if (gv[j]) region[cl*RSTR + tid + j*256] = fbc[(size_t)cl*HWSZ + goff[j]];
    }
    __syncthreads();

    if (tid < 9*RCL) {
        const int pp = tid >> 3, cl = tid & (RCL-1);
        const float* rc = region + cl*RSTR;
        float acc = 0.f;
        #pragma unroll
        for (int q = 0; q < 4; q++) {
            int s = pp*4 + q;
            acc += __int_as_float(sg[8  +s]) * rc[sg[152+s]]
                 + __int_as_float(sg[44 +s]) * rc[sg[188+s]]
                 + __int_as_float(sg[80 +s]) * rc[sg[224+s]]
                 + __int_as_float(sg[116+s]) * rc[sg[260+s]];
        }
        xout[(size_t)n*FDIM + pp*NCH + c0 + cl] = acc;
    }
}

// ---------------- fp32 TN GEMM with register prefetch ----------------
struct Ptrs3 {
    const float* A[3];
    const float* W[3];
    float* C[3];
};

template<bool RELU, bool SPLITK, int BM>
__global__ __launch_bounds__(256) void gemm_kernel(Ptrs3 p, int M, int N, int K, int kChunk)
{
    constexpr int RM   = BM/16;
    constexpr int ANUM = (BM == 64) ? 8 : 4;
    __shared__ float As[32*BM];
    __shared__ float Bs[32*64];
    const int z = blockIdx.z;
    const float* A; const float* W; float* C;
    int k0, k1;
    if (SPLITK) {
        A = p.A[0]; W = p.W[0];
        k0 = z * kChunk; k1 = k0 + kChunk;
        C = p.C[0] + (size_t)z * M * N;
    } else {
        A = p.A[z]; W = p.W[z]; C = p.C[z];
        k0 = 0; k1 = K;
    }
    const int tid = threadIdx.x;
    const int m0 = blockIdx.x * BM, n0 = blockIdx.y * 64;
    const int lrowA = (BM == 64) ? (tid >> 2) : (tid >> 3);
    const int lkA   = (BM == 64) ? (tid & 3) * 8 : (tid & 7) * 4;
    const int lrowB = tid >> 2;
    const int lkB   = (tid & 3) * 8;
    const float* Ald = A + (size_t)(m0 + lrowA) * K + k0 + lkA;
    const float* Wld = W + (size_t)(n0 + lrowB) * K + k0 + lkB;
    const int ty = tid >> 4, tx = tid & 15;
    float acc[RM][4] = {};
    float aR[ANUM], bR[8];

    *(f4v*)&aR[0] = *(const f4v*)Ald;
    if (BM == 64) *(f4v*)&aR[4] = *(const f4v*)(Ald + 4);
    *(f4v*)&bR[0] = *(const f4v*)Wld;
    *(f4v*)&bR[4] = *(const f4v*)(Wld + 4);

    for (int kt = k0; kt < k1; kt += 32) {
        __syncthreads();
        #pragma unroll
        for (int t = 0; t < ANUM; t++) As[(lkA+t)*BM + lrowA] = aR[t];
        #pragma unroll
        for (int t = 0; t < 8; t++)    Bs[(lkB+t)*64 + lrowB] = bR[t];
        __syncthreads();
        if (kt + 32 < k1) {
            Ald += 32; Wld += 32;
            *(f4v*)&aR[0] = *(const f4v*)Ald;
            if (BM == 64) *(f4v*)&aR[4] = *(const f4v*)(Ald + 4);
            *(f4v*)&bR[0] = *(const f4v*)Wld;
            *(f4v*)&bR[4] = *(const f4v*)(Wld + 4);
        }
        #pragma unroll 4
        for (int k = 0; k < 32; k++) {
            float av[RM];
            if (RM == 4) {
                f4v t = *(const f4v*)&As[k*BM + ty*4];
                av[0]=t[0]; av[1]=t[1]; av[2]=t[2]; av[3]=t[3];
            } else {
                av[0] = As[k*BM + ty*2];
                av[1] = As[k*BM + ty*2 + 1];
            }
            f4v bv = *(const f4v*)&Bs[k*64 + tx*4];
            #pragma unroll
            for (int i = 0; i < RM; i++)
                #pragma unroll
                for (int j = 0; j < 4; j++)
                    acc[i][j] += av[i]*bv[j];
        }
    }
    float* Cp = C + (size_t)(m0 + ty*RM) * N + n0 + tx*4;
    #pragma unroll
    for (int i = 0; i < RM; i++) {
        f4v r;
        #pragma unroll
        for (int j = 0; j < 4; j++)
            r[j] = RELU ? fmaxf(acc[i][j], 0.0f) : acc[i][j];
        *(f4v*)(Cp + (size_t)i * N) = r;
    }
}

// ---------------- split-K reduce + relu ----------------
__global__ __launch_bounds__(256) void reduce_relu_kernel(
    const float* __restrict__ pin, float* __restrict__ hout)
{
    int i = blockIdx.x * 256 + threadIdx.x;
    const f4v* p4 = (const f4v*)pin;
    f4v a = p4[i];
    a += p4[i + MN/4];
    a += p4[i + 2*(MN/4)];
    a += p4[i + 3*(MN/4)];
    f4v r;
    #pragma unroll
    for (int j = 0; j < 4; j++) r[j] = fmaxf(a[j], 0.0f);
    ((f4v*)hout)[i] = r;
}

// ---------------- final heads (GEMV, one wave per roi) ----------------
__global__ __launch_bounds__(256) void heads_kernel(
    const float* __restrict__ c2, const float* __restrict__ i2, const float* __restrict__ r2,
    const float* __restrict__ wc3, const float* __restrict__ bc3,
    const float* __restrict__ wi3, const float* __restrict__ bi3,
    const float* __restrict__ wr3, const float* __restrict__ br3,
    float* __restrict__ out)
{
    const int lane = threadIdx.x & 63;
    const int wv   = threadIdx.x >> 6;
    const int n    = blockIdx.x * 4 + wv;
    const float* cr = c2 + (size_t)n*256;
    const float* ir = i2 + (size_t)n*256;
    const float* rr = r2 + (size_t)n*256;
    float vc = 0.0f, vi = 0.0f, vr[7] = {};
    #pragma unroll
    for (int j = 0; j < 4; j++) {
        int k = lane + j*64;
        float cv = cr[k], iv = ir[k], rv = rr[k];
        vc += cv * wc3[k];
        vi += iv * wi3[k];
        #pragma unroll
        for (int t = 0; t < 7; t++) vr[t] += rv * wr3[t*256 + k];
    }
    #pragma unroll
    for (int off = 32; off > 0; off >>= 1) {
        vc += __shfl_down(vc, off, 64);
        vi += __shfl_down(vi, off, 64);
        #pragma unroll
        for (int t = 0; t < 7; t++) vr[t] += __shfl_down(vr[t], off, 64);
    }
    if (lane == 0) {
        out[n]        = vc + bc3[0];
        out[2048 + n] = vi + bi3[0];
        #pragma unroll
        for (int t = 0; t < 7; t++) out[4096 + n*7 + t] = vr[t] + br3[t];
    }
}

extern "C" void kernel_launch(void* const* d_in, const int* in_sizes, int n_in,
                              void* d_out, int out_size, void* d_ws, size_t ws_size,
                              hipStream_t stream)
{
    const float* fm    = (const float*)d_in[0];
    const float* boxes = (const float*)d_in[1];
    const int*   bidx  = (const int*)d_in[2];
    const float* w_sh1 = (const float*)d_in[3];
    const float* w_sh2 = (const float*)d_in[4];
    const float* w_c1  = (const float*)d_in[5];
    const float* w_c2  = (const float*)d_in[6];
    const float* w_c3  = (const float*)d_in[7];
    const float* b_c3  = (const float*)d_in[8];
    const float* w_i1  = (const float*)d_in[9];
    const float* w_i2  = (const float*)d_in[10];
    const float* w_i3  = (const float*)d_in[11];
    const float* b_i3  = (const float*)d_in[12];
    const float* w_r1  = (const float*)d_in[13];
    const float* w_r2  = (const float*)d_in[14];
    const float* w_r3  = (const float*)d_in[15];
    const float* b_r3  = (const float*)d_in[16];
    float* out = (float*)d_out;

    // ws layout (floats): xbuf 4,718,592 | h1 524,288 | sh 524,288 | part 2,097,152
    // geo (2048*296 ints = 606,208) aliases part (dead by the time gemm1 writes part).
    float* ws   = (float*)d_ws;
    float* xbuf = ws;
    float* h1   = xbuf + (size_t)2048*2304;
    float* sh   = h1 + MN;
    float* part = sh + MN;
    int*   geo  = (int*)part;
    float* b1c  = xbuf;            // alias region: 6 x MN fits in xbuf
    float* b1i  = b1c + MN;
    float* b1r  = b1i + MN;
    float* b2c  = b1r + MN;
    float* b2i  = b2c + MN;
    float* b2r  = b2i + MN;

    geo_kernel<<<NROI/4, 256, 0, stream>>>(boxes, bidx, geo);
    roi_kernel<<<dim3(NROI, NCH/RCL), 256, 0, stream>>>(fm, geo, xbuf);

    Ptrs3 g1;
    g1.A[0]=xbuf; g1.A[1]=xbuf; g1.A[2]=xbuf;
    g1.W[0]=w_sh1; g1.W[1]=w_sh1; g1.W[2]=w_sh1;
    g1.C[0]=part; g1.C[1]=part; g1.C[2]=part;
    gemm_kernel<false,true,64><<<dim3(32,4,4), 256, 0, stream>>>(g1, 2048, 256, 2304, 576);

    reduce_relu_kernel<<<MN/4/256, 256, 0, stream>>>(part, h1);

    Ptrs3 g2;
    g2.A[0]=h1; g2.A[1]=h1; g2.A[2]=h1;
    g2.W[0]=w_sh2; g2.W[1]=w_sh2; g2.W[2]=w_sh2;
    g2.C[0]=sh; g2.C[1]=sh; g2.C[2]=sh;
    gemm_kernel<true,false,32><<<dim3(64,4,1), 256, 0, stream>>>(g2, 2048, 256, 256, 0);

    Ptrs3 g3;
    g3.A[0]=sh; g3.A[1]=sh; g3.A[2]=sh;
    g3.W[0]=w_c1; g3.W[1]=w_i1; g3.W[2]=w_r1;
    g3.C[0]=b1c; g3.C[1]=b1i; g3.C[2]=b1r;
    gemm_kernel<true,false,32><<<dim3(64,4,3), 256, 0, stream>>>(g3, 2048, 256, 256, 0);

    Ptrs3 g4;
    g4.A[0]=b1c; g4.A[1]=b1i; g4.A[2]=b1r;
    g4.W[0]=w_c2; g4.W[1]=w_i2; g4.W[2]=w_r2;
    g4.C[0]=b2c; g4.C[1]=b2i; g4.C[2]=b2r;
    gemm_kernel<true,false,32><<<dim3(64,4,3), 256, 0, stream>>>(g4, 2048, 256, 256, 0);

    heads_kernel<<<NROI/4, 256, 0, stream>>>(b2c, b2i, b2r,
                                             w_c3, b_c3, w_i3, b_i3, w_r3, b_r3, out);
}

// Round 3
// 535.412 us; speedup vs baseline: 1.2394x; 1.1891x over previous
//
#include <hip/hip_runtime.h>
#include <hip/hip_fp16.h>

typedef float f4v __attribute__((ext_vector_type(4)));

#define NROI 2048
#define NCH  256
#define MAPH 256
#define MAPW 256
#define HWSZ (MAPH*MAPW)
#define FDIM 2304
#define MN   (2048*256)

// ================= PATH A: HWC fp16 =================

// ---- CHW fp32 -> HWC fp16 transpose: tile 64ch x 64x per (b,y) ----
__global__ __launch_bounds__(256) void transpose_kernel(
    const float* __restrict__ fm, __half* __restrict__ hwc)
{
    __shared__ float tile[64*65];
    const int tid = threadIdx.x;
    const int x0 = blockIdx.x * 64, c0 = blockIdx.y * 64;
    const int bz = blockIdx.z;
    const int b = bz >> 8, y = bz & 255;

    const int lane = tid & 63, cg = tid >> 6;           // cg 0..3
    const float* src = fm + (((size_t)b*NCH + c0 + cg*16)*MAPH + y)*MAPW + x0 + lane;
    #pragma unroll
    for (int i = 0; i < 16; i++)
        tile[(cg*16 + i)*65 + lane] = src[(size_t)i * HWSZ];
    __syncthreads();

    __half* dst = hwc + (((size_t)b*MAPH + y)*MAPW + x0)*NCH + c0;
    const int c2 = (tid & 31) * 2;
    const int xb = tid >> 5;                            // 0..7
    #pragma unroll
    for (int k = 0; k < 8; k++) {
        int x = xb + k*8;
        float f0 = tile[c2*65 + x];
        float f1 = tile[(c2+1)*65 + x];
        *(__half2*)(dst + (size_t)x*NCH + c2) = __floats2half2_rn(f0, f1);
    }
}

// ---- RoI align from HWC fp16: 2 rois/block, thread = channel pair ----
__global__ __launch_bounds__(256) void roi_hwc_kernel(
    const __half* __restrict__ hwc, const float* __restrict__ boxes,
    const int* __restrict__ bidx, float* __restrict__ xout)
{
    const int tid = threadIdx.x;
    const int r   = tid >> 7;          // roi slot in block
    const int lt  = tid & 127;         // local thread: channel pair index
    const int n   = blockIdx.x * 2 + r;

    __shared__ float sw[2][4][36];
    __shared__ int   soff[2][4][36];
    __shared__ int   sb[2];

    if (lt < 36) {
        float b0 = boxes[n*7+0], b1 = boxes[n*7+1];
        float b4 = boxes[n*7+4], b5 = boxes[n*7+5], b6 = boxes[n*7+6];
        float cx = (b0 + 51.2f) / 0.4f - 0.5f;
        float cy = (b1 + 51.2f) / 0.4f - 0.5f;
        float w  = b5 / 0.4f;
        float h  = b4 / 0.4f;
        float th = -b6;
        float ct = cosf(th), st = sinf(th);
        float binh = h / 3.0f, binw = w / 3.0f;
        int s  = lt;
        int ph = s / 12, pw = (s % 12) / 4, sy = (s % 4) / 2, sx = s & 1;
        float sgy = ((float)sy + 0.5f) * 0.5f;
        float sgx = ((float)sx + 0.5f) * 0.5f;
        float yy  = -h*0.5f + ((float)ph + sgy) * binh;
        float xxl = -w*0.5f + ((float)pw + sgx) * binw;
        float y = yy*ct - xxl*st + cy;
        float x = yy*st + xxl*ct + cx;
        bool valid = (y > -1.0f) && (y < 256.0f) && (x > -1.0f) && (x < 256.0f);
        y = fminf(fmaxf(y, 0.0f), 255.0f);
        x = fminf(fmaxf(x, 0.0f), 255.0f);
        int y0 = (int)floorf(y); if (y0 > 255) y0 = 255;
        int x0 = (int)floorf(x); if (x0 > 255) x0 = 255;
        int y1 = min(y0+1, 255), x1 = min(x0+1, 255);
        float ly = y - (float)y0, lx = x - (float)x0;
        float hy = 1.0f - ly, hx = 1.0f - lx;
        float v = valid ? 0.25f : 0.0f;
        sw[r][0][s] = hy*hx*v; sw[r][1][s] = hy*lx*v;
        sw[r][2][s] = ly*hx*v; sw[r][3][s] = ly*lx*v;
        soff[r][0][s] = (y0*MAPW + x0)*NCH;
        soff[r][1][s] = (y0*MAPW + x1)*NCH;
        soff[r][2][s] = (y1*MAPW + x0)*NCH;
        soff[r][3][s] = (y1*MAPW + x1)*NCH;
    }
    if (lt == 0) sb[r] = bidx[n];
    __syncthreads();

    const __half* base = hwc + (size_t)sb[r]*(HWSZ*NCH) + lt*2;
    float* xo = xout + (size_t)n*FDIM + lt*2;

    #pragma unroll 3
    for (int pp = 0; pp < 9; pp++) {
        float ax = 0.f, ay = 0.f;
        #pragma unroll
        for (int q = 0; q < 4; q++) {
            int s = pp*4 + q;
            #pragma unroll
            for (int c = 0; c < 4; c++) {
                __half2 v = *(const __half2*)(base + soff[r][c][s]);
                float2 f = __half22float2(v);
                float wgt = sw[r][c][s];
                ax += wgt * f.x;
                ay += wgt * f.y;
            }
        }
        float2 o; o.x = ax; o.y = ay;
        *(float2*)(xo + pp*NCH) = o;
    }
}

// ================= PATH B fallback (round-2 kernels) =================
#define GSTR 296

__global__ __launch_bounds__(256) void geo_kernel(
    const float* __restrict__ boxes, const int* __restrict__ bidx,
    int* __restrict__ geo)
{
    const int lane = threadIdx.x & 63;
    const int n = blockIdx.x * 4 + (threadIdx.x >> 6);

    int y0 = 255, x0 = 255, y1 = 0, x1 = 0;
    float w00 = 0.f, w01 = 0.f, w10 = 0.f, w11 = 0.f;
    if (lane < 36) {
        float b0 = boxes[n*7+0], b1 = boxes[n*7+1];
        float b4 = boxes[n*7+4], b5 = boxes[n*7+5], b6 = boxes[n*7+6];
        float cx = (b0 + 51.2f) / 0.4f - 0.5f;
        float cy = (b1 + 51.2f) / 0.4f - 0.5f;
        float w  = b5 / 0.4f;
        float h  = b4 / 0.4f;
        float th = -b6;
        float ct = cosf(th), st = sinf(th);
        float binh = h / 3.0f, binw = w / 3.0f;
        int s  = lane;
        int ph = s / 12, pw = (s % 12) / 4, sy = (s % 4) / 2, sx = s & 1;
        float sgy = ((float)sy + 0.5f) * 0.5f;
        float sgx = ((float)sx + 0.5f) * 0.5f;
        float yy  = -h*0.5f + ((float)ph + sgy) * binh;
        float xxl = -w*0.5f + ((float)pw + sgx) * binw;
        float y = yy*ct - xxl*st + cy;
        float x = yy*st + xxl*ct + cx;
        bool valid = (y > -1.0f) && (y < 256.0f) && (x > -1.0f) && (x < 256.0f);
        y = fminf(fmaxf(y, 0.0f), 255.0f);
        x = fminf(fmaxf(x, 0.0f), 255.0f);
        y0 = (int)floorf(y); if (y0 > 255) y0 = 255;
        x0 = (int)floorf(x); if (x0 > 255) x0 = 255;
        y1 = min(y0+1, 255); x1 = min(x0+1, 255);
        float ly = y - (float)y0, lx = x - (float)x0;
        float hy = 1.0f - ly, hx = 1.0f - lx;
        float v = valid ? 0.25f : 0.0f;
        w00 = hy*hx*v; w01 = hy*lx*v; w10 = ly*hx*v; w11 = ly*lx*v;
    }
    int ylo = y0, xlo = x0, yhi = y1, xhi = x1;
    #pragma unroll
    for (int off = 32; off; off >>= 1) {
        ylo = min(ylo, __shfl_xor(ylo, off));
        xlo = min(xlo, __shfl_xor(xlo, off));
        yhi = max(yhi, __shfl_xor(yhi, off));
        xhi = max(xhi, __shfl_xor(xhi, off));
    }
    const int rw = xhi - xlo + 1;
    const int rh = yhi - ylo + 1;
    int* g = geo + (size_t)n * GSTR;
    if (lane == 0) {
        g[0] = ylo; g[1] = xlo; g[2] = rh * rw; g[3] = rw;
        g[4] = (int)((1u << 22) / (unsigned)rw + 1u);
        g[5] = bidx[n];
    }
    if (lane < 36) {
        g[8   + lane] = __float_as_int(w00);
        g[44  + lane] = __float_as_int(w01);
        g[80  + lane] = __float_as_int(w10);
        g[116 + lane] = __float_as_int(w11);
        g[152 + lane] = (y0 - ylo)*rw + (x0 - xlo);
        g[188 + lane] = (y0 - ylo)*rw + (x1 - xlo);
        g[224 + lane] = (y1 - ylo)*rw + (x0 - xlo);
        g[260 + lane] = (y1 - ylo)*rw + (x1 - xlo);
    }
}

#define RCL  8
#define RMAX 24
#define RSTR (RMAX*RMAX + 1)

__global__ __launch_bounds__(256, 8) void roi_kernel(
    const float* __restrict__ fm, const int* __restrict__ geo,
    float* __restrict__ xout)
{
    const int n   = blockIdx.x;
    const int c0  = blockIdx.y * RCL;
    const int tid = threadIdx.x;

    __shared__ int   sg[GSTR];
    __shared__ float region[RCL * RSTR];

    for (int i = tid; i < GSTR; i += 256) sg[i] = geo[(size_t)n * GSTR + i];
    __syncthreads();

    const int ylo = sg[0], xlo = sg[1], area = sg[2], rw = sg[3];
    const unsigned mg = (unsigned)sg[4];
    const int b = sg[5];

    int  goff[3];
    bool gv[3];
    #pragma unroll
    for (int j = 0; j < 3; j++) {
        int idx = tid + j*256;
        gv[j] = idx < area;
        unsigned yy = ((unsigned)idx * mg) >> 22;
        int xx = idx - (int)yy * rw;
        goff[j] = (int)yy * MAPW + xx;
    }
    const float* __restrict__ fbc =
        fm + ((size_t)b * NCH + c0) * HWSZ + ylo * MAPW + xlo;

    #pragma unroll
    for (int cl = 0; cl < RCL; cl++) {
        #pragma unroll
        for (int j = 0; j < 3; j++)
            if (gv[j]) region[cl*RSTR + tid + j*256] = fbc[(size_t)cl*HWSZ + goff[j]];
    }
    __syncthreads();

    if (tid < 9*RCL) {
        const int pp = tid >> 3, cl = tid & (RCL-1);
        const float* rc = region + cl*RSTR;
        float acc = 0.f;
        #pragma unroll
        for (int q = 0; q < 4; q++) {
            int s = pp*4 + q;
            acc += __int_as_float(sg[8  +s]) * rc[sg[152+s]]
                 + __int_as_float(sg[44 +s]) * rc[sg[188+s]]
                 + __int_as_float(sg[80 +s]) * rc[sg[224+s]]
                 + __int_as_float(sg[116+s]) * rc[sg[260+s]];
        }
        xout[(size_t)n*FDIM + pp*NCH + c0 + cl] = acc;
    }
}

// ================= fp32 TN GEMM with register prefetch =================
struct Ptrs3 {
    const float* A[3];
    const float* W[3];
    float* C[3];
};

template<bool RELU, bool SPLITK, int BM>
__global__ __launch_bounds__(256) void gemm_kernel(Ptrs3 p, int M, int N, int K, int kChunk)
{
    constexpr int RM   = BM/16;
    constexpr int ANUM = (BM == 64) ? 8 : 4;
    __shared__ float As[32*BM];
    __shared__ float Bs[32*64];
    const int z = blockIdx.z;
    const float* A; const float* W; float* C;
    int k0, k1;
    if (SPLITK) {
        A = p.A[0]; W = p.W[0];
        k0 = z * kChunk; k1 = k0 + kChunk;
        C = p.C[0] + (size_t)z * M * N;
    } else {
        A = p.A[z]; W = p.W[z]; C = p.C[z];
        k0 = 0; k1 = K;
    }
    const int tid = threadIdx.x;
    const int m0 = blockIdx.x * BM, n0 = blockIdx.y * 64;
    const int lrowA = (BM == 64) ? (tid >> 2) : (tid >> 3);
    const int lkA   = (BM == 64) ? (tid & 3) * 8 : (tid & 7) * 4;
    const int lrowB = tid >> 2;
    const int lkB   = (tid & 3) * 8;
    const float* Ald = A + (size_t)(m0 + lrowA) * K + k0 + lkA;
    const float* Wld = W + (size_t)(n0 + lrowB) * K + k0 + lkB;
    const int ty = tid >> 4, tx = tid & 15;
    float acc[RM][4] = {};
    float aR[ANUM], bR[8];

    *(f4v*)&aR[0] = *(const f4v*)Ald;
    if (BM == 64) *(f4v*)&aR[4] = *(const f4v*)(Ald + 4);
    *(f4v*)&bR[0] = *(const f4v*)Wld;
    *(f4v*)&bR[4] = *(const f4v*)(Wld + 4);

    for (int kt = k0; kt < k1; kt += 32) {
        __syncthreads();
        #pragma unroll
        for (int t = 0; t < ANUM; t++) As[(lkA+t)*BM + lrowA] = aR[t];
        #pragma unroll
        for (int t = 0; t < 8; t++)    Bs[(lkB+t)*64 + lrowB] = bR[t];
        __syncthreads();
        if (kt + 32 < k1) {
            Ald += 32; Wld += 32;
            *(f4v*)&aR[0] = *(const f4v*)Ald;
            if (BM == 64) *(f4v*)&aR[4] = *(const f4v*)(Ald + 4);
            *(f4v*)&bR[0] = *(const f4v*)Wld;
            *(f4v*)&bR[4] = *(const f4v*)(Wld + 4);
        }
        #pragma unroll 4
        for (int k = 0; k < 32; k++) {
            float av[RM];
            if (RM == 4) {
                f4v t = *(const f4v*)&As[k*BM + ty*4];
                av[0]=t[0]; av[1]=t[1]; av[2]=t[2]; av[3]=t[3];
            } else {
                av[0] = As[k*BM + ty*2];
                av[1] = As[k*BM + ty*2 + 1];
            }
            f4v bv = *(const f4v*)&Bs[k*64 + tx*4];
            #pragma unroll
            for (int i = 0; i < RM; i++)
                #pragma unroll
                for (int j = 0; j < 4; j++)
                    acc[i][j] += av[i]*bv[j];
        }
    }
    float* Cp = C + (size_t)(m0 + ty*RM) * N + n0 + tx*4;
    #pragma unroll
    for (int i = 0; i < RM; i++) {
        f4v r;
        #pragma unroll
        for (int j = 0; j < 4; j++)
            r[j] = RELU ? fmaxf(acc[i][j], 0.0f) : acc[i][j];
        *(f4v*)(Cp + (size_t)i * N) = r;
    }
}

__global__ __launch_bounds__(256) void reduce_relu_kernel(
    const float* __restrict__ pin, float* __restrict__ hout)
{
    int i = blockIdx.x * 256 + threadIdx.x;
    const f4v* p4 = (const f4v*)pin;
    f4v a = p4[i];
    a += p4[i + MN/4];
    a += p4[i + 2*(MN/4)];
    a += p4[i + 3*(MN/4)];
    f4v r;
    #pragma unroll
    for (int j = 0; j < 4; j++) r[j] = fmaxf(a[j], 0.0f);
    ((f4v*)hout)[i] = r;
}

__global__ __launch_bounds__(256) void heads_kernel(
    const float* __restrict__ c2, const float* __restrict__ i2, const float* __restrict__ r2,
    const float* __restrict__ wc3, const float* __restrict__ bc3,
    const float* __restrict__ wi3, const float* __restrict__ bi3,
    const float* __restrict__ wr3, const float* __restrict__ br3,
    float* __restrict__ out)
{
    const int lane = threadIdx.x & 63;
    const int wv   = threadIdx.x >> 6;
    const int n    = blockIdx.x * 4 + wv;
    const float* cr = c2 + (size_t)n*256;
    const float* ir = i2 + (size_t)n*256;
    const float* rr = r2 + (size_t)n*256;
    float vc = 0.0f, vi = 0.0f, vr[7] = {};
    #pragma unroll
    for (int j = 0; j < 4; j++) {
        int k = lane + j*64;
        float cv = cr[k], iv = ir[k], rv = rr[k];
        vc += cv * wc3[k];
        vi += iv * wi3[k];
        #pragma unroll
        for (int t = 0; t < 7; t++) vr[t] += rv * wr3[t*256 + k];
    }
    #pragma unroll
    for (int off = 32; off > 0; off >>= 1) {
        vc += __shfl_down(vc, off, 64);
        vi += __shfl_down(vi, off, 64);
        #pragma unroll
        for (int t = 0; t < 7; t++) vr[t] += __shfl_down(vr[t], off, 64);
    }
    if (lane == 0) {
        out[n]        = vc + bc3[0];
        out[2048 + n] = vi + bi3[0];
        #pragma unroll
        for (int t = 0; t < 7; t++) out[4096 + n*7 + t] = vr[t] + br3[t];
    }
}

extern "C" void kernel_launch(void* const* d_in, const int* in_sizes, int n_in,
                              void* d_out, int out_size, void* d_ws, size_t ws_size,
                              hipStream_t stream)
{
    const float* fm    = (const float*)d_in[0];
    const float* boxes = (const float*)d_in[1];
    const int*   bidx  = (const int*)d_in[2];
    const float* w_sh1 = (const float*)d_in[3];
    const float* w_sh2 = (const float*)d_in[4];
    const float* w_c1  = (const float*)d_in[5];
    const float* w_c2  = (const float*)d_in[6];
    const float* w_c3  = (const float*)d_in[7];
    const float* b_c3  = (const float*)d_in[8];
    const float* w_i1  = (const float*)d_in[9];
    const float* w_i2  = (const float*)d_in[10];
    const float* w_i3  = (const float*)d_in[11];
    const float* b_i3  = (const float*)d_in[12];
    const float* w_r1  = (const float*)d_in[13];
    const float* w_r2  = (const float*)d_in[14];
    const float* w_r3  = (const float*)d_in[15];
    const float* b_r3  = (const float*)d_in[16];
    float* out = (float*)d_out;

    // ws (floats): xbuf 4,718,592 | h1 524,288 | sh 524,288 | part 2,097,152 | hwc (fp16, 64M halves)
    float* ws   = (float*)d_ws;
    float* xbuf = ws;
    float* h1   = xbuf + (size_t)2048*2304;
    float* sh   = h1 + MN;
    float* part = sh + MN;
    int*   geo  = (int*)part;                 // fallback path only
    __half* hwc = (__half*)(part + (size_t)4*MN);
    float* b1c  = xbuf;
    float* b1i  = b1c + MN;
    float* b1r  = b1i + MN;
    float* b2c  = b1r + MN;
    float* b2i  = b2c + MN;
    float* b2r  = b2i + MN;

    const size_t need = (size_t)(7864320) * 4 + (size_t)4*NCH*HWSZ * sizeof(__half);

    if (ws_size >= need) {
        transpose_kernel<<<dim3(MAPW/64, NCH/64, 4*MAPH), 256, 0, stream>>>(fm, hwc);
        roi_hwc_kernel<<<NROI/2, 256, 0, stream>>>(hwc, boxes, bidx, xbuf);
    } else {
        geo_kernel<<<NROI/4, 256, 0, stream>>>(boxes, bidx, geo);
        roi_kernel<<<dim3(NROI, NCH/RCL), 256, 0, stream>>>(fm, geo, xbuf);
    }

    Ptrs3 g1;
    g1.A[0]=xbuf; g1.A[1]=xbuf; g1.A[2]=xbuf;
    g1.W[0]=w_sh1; g1.W[1]=w_sh1; g1.W[2]=w_sh1;
    g1.C[0]=part; g1.C[1]=part; g1.C[2]=part;
    gemm_kernel<false,true,64><<<dim3(32,4,4), 256, 0, stream>>>(g1, 2048, 256, 2304, 576);

    reduce_relu_kernel<<<MN/4/256, 256, 0, stream>>>(part, h1);

    Ptrs3 g2;
    g2.A[0]=h1; g2.A[1]=h1; g2.A[2]=h1;
    g2.W[0]=w_sh2; g2.W[1]=w_sh2; g2.W[2]=w_sh2;
    g2.C[0]=sh; g2.C[1]=sh; g2.C[2]=sh;
    gemm_kernel<true,false,32><<<dim3(64,4,1), 256, 0, stream>>>(g2, 2048, 256, 256, 0);

    Ptrs3 g3;
    g3.A[0]=sh; g3.A[1]=sh; g3.A[2]=sh;
    g3.W[0]=w_c1; g3.W[1]=w_i1; g3.W[2]=w_r1;
    g3.C[0]=b1c; g3.C[1]=b1i; g3.C[2]=b1r;
    gemm_kernel<true,false,32><<<dim3(64,4,3), 256, 0, stream>>>(g3, 2048, 256, 256, 0);

    Ptrs3 g4;
    g4.A[0]=b1c; g4.A[1]=b1i; g4.A[2]=b1r;
    g4.W[0]=w_c2; g4.W[1]=w_i2; g4.W[2]=w_r2;
    g4.C[0]=b2c; g4.C[1]=b2i; g4.C[2]=b2r;
    gemm_kernel<true,false,32><<<dim3(64,4,3), 256, 0, stream>>>(g4, 2048, 256, 256, 0);

    heads_kernel<<<NROI/4, 256, 0, stream>>>(b2c, b2i, b2r,
                                             w_c3, b_c3, w_i3, b_i3, w_r3, b_r3, out);
}

// Round 4
// 474.515 us; speedup vs baseline: 1.3985x; 1.1283x over previous
//
#include <hip/hip_runtime.h>
#include <hip/hip_fp16.h>

typedef float f4v __attribute__((ext_vector_type(4)));
typedef _Float16 h4 __attribute__((ext_vector_type(4)));
typedef _Float16 h8 __attribute__((ext_vector_type(8)));

#define NROI 2048
#define NCH  256
#define MAPH 256
#define MAPW 256
#define HWSZ (MAPH*MAPW)
#define FDIM 2304
#define MN   (2048*256)

// wbuf (fp16 weights) offsets in halfs
#define O_SH1 0
#define O_SH2 589824
#define O_C1  655360
#define O_C2  720896
#define O_I1  786432
#define O_I2  851968
#define O_R1  917504
#define O_R2  983040
#define WTOT  1048576

// ---- weight fp32 -> fp16 convert: 2048 blocks x 512 floats ----
__global__ __launch_bounds__(256) void convert_w_kernel(
    const float* __restrict__ s1, const float* __restrict__ s2,
    const float* __restrict__ c1, const float* __restrict__ c2,
    const float* __restrict__ i1, const float* __restrict__ i2,
    const float* __restrict__ r1, const float* __restrict__ r2,
    __half* __restrict__ wbuf)
{
    const int b = blockIdx.x, t = threadIdx.x;
    const float* src;
    int base;
    if (b < 1152) { src = s1 + (size_t)b*512; base = b*512; }
    else {
        int j  = (b - 1152) >> 7;
        int lb = (b - 1152) & 127;
        switch (j) {
            case 0: src = s2; break; case 1: src = c1; break;
            case 2: src = c2; break; case 3: src = i1; break;
            case 4: src = i2; break; case 5: src = r1; break;
            default: src = r2; break;
        }
        src += (size_t)lb*512;
        base = 589824 + (b - 1152)*512;
    }
    float2 v = *(const float2*)(src + t*2);
    *(__half2*)(wbuf + base + t*2) = __floats2half2_rn(v.x, v.y);
}

// ---- CHW fp32 -> HWC fp16 transpose ----
__global__ __launch_bounds__(256) void transpose_kernel(
    const float* __restrict__ fm, __half* __restrict__ hwc)
{
    __shared__ float tile[64*65];
    const int tid = threadIdx.x;
    const int x0 = blockIdx.x * 64, c0 = blockIdx.y * 64;
    const int bz = blockIdx.z;
    const int b = bz >> 8, y = bz & 255;

    const int lane = tid & 63, cg = tid >> 6;
    const float* src = fm + (((size_t)b*NCH + c0 + cg*16)*MAPH + y)*MAPW + x0 + lane;
    #pragma unroll
    for (int i = 0; i < 16; i++)
        tile[(cg*16 + i)*65 + lane] = src[(size_t)i * HWSZ];
    __syncthreads();

    __half* dst = hwc + (((size_t)b*MAPH + y)*MAPW + x0)*NCH + c0;
    const int c2 = (tid & 31) * 2;
    const int xb = tid >> 5;
    #pragma unroll
    for (int k = 0; k < 8; k++) {
        int x = xb + k*8;
        float f0 = tile[c2*65 + x];
        float f1 = tile[(c2+1)*65 + x];
        *(__half2*)(dst + (size_t)x*NCH + c2) = __floats2half2_rn(f0, f1);
    }
}

// ---- RoI align from HWC fp16, fp16 x output ----
__global__ __launch_bounds__(256) void roi_hwc_kernel(
    const __half* __restrict__ hwc, const float* __restrict__ boxes,
    const int* __restrict__ bidx, __half* __restrict__ xout)
{
    const int tid = threadIdx.x;
    const int r   = tid >> 7;
    const int lt  = tid & 127;
    const int n   = blockIdx.x * 2 + r;

    __shared__ float sw[2][4][36];
    __shared__ int   soff[2][4][36];
    __shared__ int   sb[2];

    if (lt < 36) {
        float b0 = boxes[n*7+0], b1 = boxes[n*7+1];
        float b4 = boxes[n*7+4], b5 = boxes[n*7+5], b6 = boxes[n*7+6];
        float cx = (b0 + 51.2f) / 0.4f - 0.5f;
        float cy = (b1 + 51.2f) / 0.4f - 0.5f;
        float w  = b5 / 0.4f;
        float h  = b4 / 0.4f;
        float th = -b6;
        float ct = cosf(th), st = sinf(th);
        float binh = h / 3.0f, binw = w / 3.0f;
        int s  = lt;
        int ph = s / 12, pw = (s % 12) / 4, sy = (s % 4) / 2, sx = s & 1;
        float sgy = ((float)sy + 0.5f) * 0.5f;
        float sgx = ((float)sx + 0.5f) * 0.5f;
        float yy  = -h*0.5f + ((float)ph + sgy) * binh;
        float xxl = -w*0.5f + ((float)pw + sgx) * binw;
        float y = yy*ct - xxl*st + cy;
        float x = yy*st + xxl*ct + cx;
        bool valid = (y > -1.0f) && (y < 256.0f) && (x > -1.0f) && (x < 256.0f);
        y = fminf(fmaxf(y, 0.0f), 255.0f);
        x = fminf(fmaxf(x, 0.0f), 255.0f);
        int y0 = (int)floorf(y); if (y0 > 255) y0 = 255;
        int x0 = (int)floorf(x); if (x0 > 255) x0 = 255;
        int y1 = min(y0+1, 255), x1 = min(x0+1, 255);
        float ly = y - (float)y0, lx = x - (float)x0;
        float hy = 1.0f - ly, hx = 1.0f - lx;
        float v = valid ? 0.25f : 0.0f;
        sw[r][0][s] = hy*hx*v; sw[r][1][s] = hy*lx*v;
        sw[r][2][s] = ly*hx*v; sw[r][3][s] = ly*lx*v;
        soff[r][0][s] = (y0*MAPW + x0)*NCH;
        soff[r][1][s] = (y0*MAPW + x1)*NCH;
        soff[r][2][s] = (y1*MAPW + x0)*NCH;
        soff[r][3][s] = (y1*MAPW + x1)*NCH;
    }
    if (lt == 0) sb[r] = bidx[n];
    __syncthreads();

    const __half* base = hwc + (size_t)sb[r]*(HWSZ*NCH) + lt*2;
    __half* xo = xout + (size_t)n*FDIM + lt*2;

    #pragma unroll 3
    for (int pp = 0; pp < 9; pp++) {
        float ax = 0.f, ay = 0.f;
        #pragma unroll
        for (int q = 0; q < 4; q++) {
            int s = pp*4 + q;
            #pragma unroll
            for (int c = 0; c < 4; c++) {
                __half2 v = *(const __half2*)(base + soff[r][c][s]);
                float2 f = __half22float2(v);
                float wgt = sw[r][c][s];
                ax += wgt * f.x;
                ay += wgt * f.y;
            }
        }
        *(__half2*)(xo + pp*NCH) = __floats2half2_rn(ax, ay);
    }
}

// ---- fp16 MFMA TN GEMM: C[m][n] = sum_k A[m][k]*W[n][k] ----
struct PtrsH {
    const __half* A[3];
    const __half* W[3];
    void* C[3];
};

__device__ inline h8 ldsH8(const _Float16* p) {
    h4 lo = *(const h4*)p;
    h4 hi = *(const h4*)(p + 4);
    return __builtin_shufflevector(lo, hi, 0,1,2,3,4,5,6,7);
}

template<bool RELU, bool SPLITK, bool OUTH>
__global__ __launch_bounds__(256) void gemm_h_kernel(PtrsH p, int M, int N, int K, int kChunk)
{
    __shared__ _Float16 As[64*40];
    __shared__ _Float16 Ws[64*40];
    const int z = blockIdx.z;
    const _Float16* A; const _Float16* W; void* C;
    int k0, k1;
    if (SPLITK) {
        A = (const _Float16*)p.A[0]; W = (const _Float16*)p.W[0];
        k0 = z * kChunk; k1 = k0 + kChunk;
        C = (char*)p.C[0] + (size_t)z * M * N * 4;
    } else {
        A = (const _Float16*)p.A[z]; W = (const _Float16*)p.W[z]; C = p.C[z];
        k0 = 0; k1 = K;
    }
    const int tid = threadIdx.x;
    const int m0 = blockIdx.x * 64, n0 = blockIdx.y * 64;
    const int srow = tid >> 2, skc = (tid & 3) * 8;
    const _Float16* Ald = A + (size_t)(m0 + srow) * K + k0 + skc;
    const _Float16* Wld = W + (size_t)(n0 + srow) * K + k0 + skc;
    const int wv = tid >> 6, lane = tid & 63;
    const int quad = lane >> 4, mr = lane & 15;

    f4v acc[4] = {};
    h8 aR = *(const h8*)Ald;
    h8 wR = *(const h8*)Wld;

    for (int kt = k0; kt < k1; kt += 32) {
        __syncthreads();
        *(h4*)&As[srow*40 + skc]     = __builtin_shufflevector(aR, aR, 0,1,2,3);
        *(h4*)&As[srow*40 + skc + 4] = __builtin_shufflevector(aR, aR, 4,5,6,7);
        *(h4*)&Ws[srow*40 + skc]     = __builtin_shufflevector(wR, wR, 0,1,2,3);
        *(h4*)&Ws[srow*40 + skc + 4] = __builtin_shufflevector(wR, wR, 4,5,6,7);
        __syncthreads();
        if (kt + 32 < k1) {
            Ald += 32; Wld += 32;
            aR = *(const h8*)Ald;
            wR = *(const h8*)Wld;
        }
        h8 af = ldsH8(&As[(wv*16 + mr)*40 + quad*8]);
        #pragma unroll
        for (int j = 0; j < 4; j++) {
            h8 bf = ldsH8(&Ws[(j*16 + mr)*40 + quad*8]);
            acc[j] = __builtin_amdgcn_mfma_f32_16x16x32_f16(af, bf, acc[j], 0, 0, 0);
        }
    }

    const int orow = m0 + wv*16 + quad*4;
    #pragma unroll
    for (int j = 0; j < 4; j++) {
        int col = n0 + j*16 + mr;
        #pragma unroll
        for (int rr = 0; rr < 4; rr++) {
            float v = acc[j][rr];
            if (RELU) v = fmaxf(v, 0.0f);
            if (OUTH) ((__half*)C)[(size_t)(orow + rr) * N + col] = __float2half(v);
            else      ((float*)C)[(size_t)(orow + rr) * N + col] = v;
        }
    }
}

// ---- split-K reduce + relu -> fp16 ----
__global__ __launch_bounds__(256) void reduce_relu_h_kernel(
    const float* __restrict__ pin, __half* __restrict__ hout)
{
    int i = blockIdx.x * 256 + threadIdx.x;
    const f4v* p4 = (const f4v*)pin;
    f4v a = p4[i];
    a += p4[i + MN/4];
    a += p4[i + 2*(MN/4)];
    a += p4[i + 3*(MN/4)];
    h4 o;
    #pragma unroll
    for (int j = 0; j < 4; j++) o[j] = (_Float16)fmaxf(a[j], 0.0f);
    *(h4*)(hout + (size_t)i*4) = o;
}

// ---- final heads (fp32 GEMV, one wave per roi) ----
__global__ __launch_bounds__(256) void heads_kernel(
    const float* __restrict__ c2, const float* __restrict__ i2, const float* __restrict__ r2,
    const float* __restrict__ wc3, const float* __restrict__ bc3,
    const float* __restrict__ wi3, const float* __restrict__ bi3,
    const float* __restrict__ wr3, const float* __restrict__ br3,
    float* __restrict__ out)
{
    const int lane = threadIdx.x & 63;
    const int wv   = threadIdx.x >> 6;
    const int n    = blockIdx.x * 4 + wv;
    const float* cr = c2 + (size_t)n*256;
    const float* ir = i2 + (size_t)n*256;
    const float* rr = r2 + (size_t)n*256;
    float vc = 0.0f, vi = 0.0f, vr[7] = {};
    #pragma unroll
    for (int j = 0; j < 4; j++) {
        int k = lane + j*64;
        float cv = cr[k], iv = ir[k], rv = rr[k];
        vc += cv * wc3[k];
        vi += iv * wi3[k];
        #pragma unroll
        for (int t = 0; t < 7; t++) vr[t] += rv * wr3[t*256 + k];
    }
    #pragma unroll
    for (int off = 32; off > 0; off >>= 1) {
        vc += __shfl_down(vc, off, 64);
        vi += __shfl_down(vi, off, 64);
        #pragma unroll
        for (int t = 0; t < 7; t++) vr[t] += __shfl_down(vr[t], off, 64);
    }
    if (lane == 0) {
        out[n]        = vc + bc3[0];
        out[2048 + n] = vi + bi3[0];
        #pragma unroll
        for (int t = 0; t < 7; t++) out[4096 + n*7 + t] = vr[t] + br3[t];
    }
}

extern "C" void kernel_launch(void* const* d_in, const int* in_sizes, int n_in,
                              void* d_out, int out_size, void* d_ws, size_t ws_size,
                              hipStream_t stream)
{
    const float* fm    = (const float*)d_in[0];
    const float* boxes = (const float*)d_in[1];
    const int*   bidx  = (const int*)d_in[2];
    const float* w_sh1 = (const float*)d_in[3];
    const float* w_sh2 = (const float*)d_in[4];
    const float* w_c1  = (const float*)d_in[5];
    const float* w_c2  = (const float*)d_in[6];
    const float* w_c3  = (const float*)d_in[7];
    const float* b_c3  = (const float*)d_in[8];
    const float* w_i1  = (const float*)d_in[9];
    const float* w_i2  = (const float*)d_in[10];
    const float* w_i3  = (const float*)d_in[11];
    const float* b_i3  = (const float*)d_in[12];
    const float* w_r1  = (const float*)d_in[13];
    const float* w_r2  = (const float*)d_in[14];
    const float* w_r3  = (const float*)d_in[15];
    const float* b_r3  = (const float*)d_in[16];
    float* out = (float*)d_out;

    // workspace layout (bytes)
    char* base = (char*)d_ws;
    __half* hwc  = (__half*)base;                                   // 128 MB
    __half* xh   = (__half*)(base + (size_t)4*NCH*HWSZ*2);          // 9 MB
    __half* h1h  = (__half*)((char*)xh + (size_t)NROI*FDIM*2);      // 1 MB
    __half* shh  = (__half*)((char*)h1h + (size_t)MN*2);            // 1 MB
    __half* b1c  = (__half*)((char*)shh + (size_t)MN*2);            // 3 MB
    __half* b1i  = b1c + MN;
    __half* b1r  = b1i + MN;
    float*  b2c  = (float*)((char*)b1c + (size_t)3*MN*2);           // 6 MB
    float*  b2i  = b2c + MN;
    float*  b2r  = b2i + MN;
    float*  part = (float*)((char*)b2c + (size_t)3*MN*4);           // 8 MB
    __half* wbuf = (__half*)((char*)part + (size_t)4*MN*4);         // 2 MB

    convert_w_kernel<<<2048, 256, 0, stream>>>(w_sh1, w_sh2, w_c1, w_c2,
                                               w_i1, w_i2, w_r1, w_r2, wbuf);
    transpose_kernel<<<dim3(MAPW/64, NCH/64, 4*MAPH), 256, 0, stream>>>(fm, hwc);
    roi_hwc_kernel<<<NROI/2, 256, 0, stream>>>(hwc, boxes, bidx, xh);

    PtrsH g1;
    g1.A[0]=g1.A[1]=g1.A[2]=xh;
    g1.W[0]=g1.W[1]=g1.W[2]=wbuf + O_SH1;
    g1.C[0]=g1.C[1]=g1.C[2]=part;
    gemm_h_kernel<false,true,false><<<dim3(32,4,4), 256, 0, stream>>>(g1, 2048, 256, 2304, 576);

    reduce_relu_h_kernel<<<MN/4/256, 256, 0, stream>>>(part, h1h);

    PtrsH g2;
    g2.A[0]=g2.A[1]=g2.A[2]=h1h;
    g2.W[0]=g2.W[1]=g2.W[2]=wbuf + O_SH2;
    g2.C[0]=g2.C[1]=g2.C[2]=shh;
    gemm_h_kernel<true,false,true><<<dim3(32,4,1), 256, 0, stream>>>(g2, 2048, 256, 256, 0);

    PtrsH g3;
    g3.A[0]=g3.A[1]=g3.A[2]=shh;
    g3.W[0]=wbuf + O_C1; g3.W[1]=wbuf + O_I1; g3.W[2]=wbuf + O_R1;
    g3.C[0]=b1c; g3.C[1]=b1i; g3.C[2]=b1r;
    gemm_h_kernel<true,false,true><<<dim3(32,4,3), 256, 0, stream>>>(g3, 2048, 256, 256, 0);

    PtrsH g4;
    g4.A[0]=b1c; g4.A[1]=b1i; g4.A[2]=b1r;
    g4.W[0]=wbuf + O_C2; g4.W[1]=wbuf + O_I2; g4.W[2]=wbuf + O_R2;
    g4.C[0]=b2c; g4.C[1]=b2i; g4.C[2]=b2r;
    gemm_h_kernel<true,false,false><<<dim3(32,4,3), 256, 0, stream>>>(g4, 2048, 256, 256, 0);

    heads_kernel<<<NROI/4, 256, 0, stream>>>(b2c, b2i, b2r,
                                             w_c3, b_c3, w_i3, b_i3, w_r3, b_r3, out);
}

// Round 5
// 471.646 us; speedup vs baseline: 1.4070x; 1.0061x over previous
//
#include <hip/hip_runtime.h>
#include <hip/hip_fp16.h>

typedef float f4v __attribute__((ext_vector_type(4)));
typedef _Float16 h4 __attribute__((ext_vector_type(4)));
typedef _Float16 h8 __attribute__((ext_vector_type(8)));

#define NROI 2048
#define NCH  256
#define MAPH 256
#define MAPW 256
#define HWSZ (MAPH*MAPW)
#define FDIM 2304
#define MN   (2048*256)

// wbuf (fp16 weights) offsets in halfs
#define O_SH1 0
#define O_SH2 589824
#define O_C1  655360
#define O_C2  720896
#define O_I1  786432
#define O_I2  851968
#define O_R1  917504
#define O_R2  983040

// ---- weight fp32 -> fp16 convert ----
__global__ __launch_bounds__(256) void convert_w_kernel(
    const float* __restrict__ s1, const float* __restrict__ s2,
    const float* __restrict__ c1, const float* __restrict__ c2,
    const float* __restrict__ i1, const float* __restrict__ i2,
    const float* __restrict__ r1, const float* __restrict__ r2,
    __half* __restrict__ wbuf)
{
    const int b = blockIdx.x, t = threadIdx.x;
    const float* src;
    int base;
    if (b < 1152) { src = s1 + (size_t)b*512; base = b*512; }
    else {
        int j  = (b - 1152) >> 7;
        int lb = (b - 1152) & 127;
        switch (j) {
            case 0: src = s2; break; case 1: src = c1; break;
            case 2: src = c2; break; case 3: src = i1; break;
            case 4: src = i2; break; case 5: src = r1; break;
            default: src = r2; break;
        }
        src += (size_t)lb*512;
        base = 589824 + (b - 1152)*512;
    }
    float2 v = *(const float2*)(src + t*2);
    *(__half2*)(wbuf + base + t*2) = __floats2half2_rn(v.x, v.y);
}

// ---- CHW fp32 -> HWC fp16 transpose, DRAM-friendly both sides ----
// block: (xtile 2) x (ctile 2) x (b*256+y). 128 ch x 128 x per block.
// reads: 512B contiguous per channel row; writes: 256B contiguous per x.
#define TP 136   // LDS row stride in halves (128 + 8 pad)

__global__ __launch_bounds__(256) void transpose_kernel(
    const float* __restrict__ fm, __half* __restrict__ hwc)
{
    __shared__ _Float16 tile[128 * TP];   // [x][c]
    const int tid = threadIdx.x;
    const int x0 = blockIdx.x * 128, c0 = blockIdx.y * 128;
    const int bz = blockIdx.z;
    const int b = bz >> 8, y = bz & 255;

    const int c    = tid & 127;
    const int half = tid >> 7;            // 0/1 -> x half
    const float* src = fm + (((size_t)b*NCH + c0 + c)*MAPH + y)*MAPW + x0 + half*64;

    #pragma unroll
    for (int j = 0; j < 16; j++) {
        f4v v = *(const f4v*)(src + j*4);
        const int xl = half*64 + j*4;
        tile[(xl+0)*TP + c] = (_Float16)v[0];
        tile[(xl+1)*TP + c] = (_Float16)v[1];
        tile[(xl+2)*TP + c] = (_Float16)v[2];
        tile[(xl+3)*TP + c] = (_Float16)v[3];
    }
    __syncthreads();

    const int cq = tid & 31;              // channel quad
    const int xb = tid >> 5;              // 0..7
    __half* dst = hwc + (((size_t)b*MAPH + y)*MAPW + x0)*NCH + c0 + cq*4;
    #pragma unroll
    for (int it = 0; it < 16; it++) {
        int x = xb + it*8;
        h4 v = *(const h4*)&tile[x*TP + cq*4];
        *(h4*)(dst + (size_t)x*NCH) = v;
    }
}

// ---- RoI align from HWC fp16: 2 rois/block, lane = channel quad, waves split pp ----
__global__ __launch_bounds__(256) void roi_hwc_kernel(
    const __half* __restrict__ hwc, const float* __restrict__ boxes,
    const int* __restrict__ bidx, __half* __restrict__ xout)
{
    const int tid  = threadIdx.x;
    const int r    = tid >> 7;         // roi slot
    const int lt   = tid & 127;
    const int wq   = lt >> 6;          // pp parity
    const int lane = lt & 63;          // channel quad index
    const int n    = blockIdx.x * 2 + r;

    __shared__ float sw[2][4][36];
    __shared__ int   soff[2][4][36];
    __shared__ int   sb[2];

    if (lt < 36) {
        float b0 = boxes[n*7+0], b1 = boxes[n*7+1];
        float b4 = boxes[n*7+4], b5 = boxes[n*7+5], b6 = boxes[n*7+6];
        float cx = (b0 + 51.2f) / 0.4f - 0.5f;
        float cy = (b1 + 51.2f) / 0.4f - 0.5f;
        float w  = b5 / 0.4f;
        float h  = b4 / 0.4f;
        float th = -b6;
        float ct = cosf(th), st = sinf(th);
        float binh = h / 3.0f, binw = w / 3.0f;
        int s  = lt;
        int ph = s / 12, pw = (s % 12) / 4, sy = (s % 4) / 2, sx = s & 1;
        float sgy = ((float)sy + 0.5f) * 0.5f;
        float sgx = ((float)sx + 0.5f) * 0.5f;
        float yy  = -h*0.5f + ((float)ph + sgy) * binh;
        float xxl = -w*0.5f + ((float)pw + sgx) * binw;
        float y = yy*ct - xxl*st + cy;
        float x = yy*st + xxl*ct + cx;
        bool valid = (y > -1.0f) && (y < 256.0f) && (x > -1.0f) && (x < 256.0f);
        y = fminf(fmaxf(y, 0.0f), 255.0f);
        x = fminf(fmaxf(x, 0.0f), 255.0f);
        int y0 = (int)floorf(y); if (y0 > 255) y0 = 255;
        int x0 = (int)floorf(x); if (x0 > 255) x0 = 255;
        int y1 = min(y0+1, 255), x1 = min(x0+1, 255);
        float ly = y - (float)y0, lx = x - (float)x0;
        float hy = 1.0f - ly, hx = 1.0f - lx;
        float v = valid ? 0.25f : 0.0f;
        sw[r][0][s] = hy*hx*v; sw[r][1][s] = hy*lx*v;
        sw[r][2][s] = ly*hx*v; sw[r][3][s] = ly*lx*v;
        soff[r][0][s] = (y0*MAPW + x0)*NCH;
        soff[r][1][s] = (y0*MAPW + x1)*NCH;
        soff[r][2][s] = (y1*MAPW + x0)*NCH;
        soff[r][3][s] = (y1*MAPW + x1)*NCH;
    }
    if (lt == 0) sb[r] = bidx[n];
    __syncthreads();

    const __half* base = hwc + (size_t)sb[r]*(HWSZ*NCH) + lane*4;
    __half* xo = xout + (size_t)n*FDIM + lane*4;

    for (int pp = wq; pp < 9; pp += 2) {
        float a0 = 0.f, a1 = 0.f, a2 = 0.f, a3 = 0.f;
        #pragma unroll
        for (int q = 0; q < 4; q++) {
            int s = pp*4 + q;
            #pragma unroll
            for (int cc = 0; cc < 4; cc++) {
                h4 v = *(const h4*)(base + soff[r][cc][s]);
                float wgt = sw[r][cc][s];
                a0 += wgt * (float)v[0];
                a1 += wgt * (float)v[1];
                a2 += wgt * (float)v[2];
                a3 += wgt * (float)v[3];
            }
        }
        h4 o; o[0]=(_Float16)a0; o[1]=(_Float16)a1; o[2]=(_Float16)a2; o[3]=(_Float16)a3;
        *(h4*)(xo + pp*NCH) = o;
    }
}

// ---- fp16 MFMA TN GEMM: C[m][n] = sum_k A[m][k]*W[n][k] ----
struct PtrsH {
    const __half* A[3];
    const __half* W[3];
    void* C[3];
};

__device__ inline h8 ldsH8(const _Float16* p) {
    h4 lo = *(const h4*)p;
    h4 hi = *(const h4*)(p + 4);
    return __builtin_shufflevector(lo, hi, 0,1,2,3,4,5,6,7);
}

template<bool RELU, bool SPLITK, bool OUTH>
__global__ __launch_bounds__(256) void gemm_h_kernel(PtrsH p, int M, int N, int K, int kChunk)
{
    __shared__ _Float16 As[64*40];
    __shared__ _Float16 Ws[64*40];
    const int z = blockIdx.z;
    const _Float16* A; const _Float16* W; void* C;
    int k0, k1;
    if (SPLITK) {
        A = (const _Float16*)p.A[0]; W = (const _Float16*)p.W[0];
        k0 = z * kChunk; k1 = k0 + kChunk;
        C = (char*)p.C[0] + (size_t)z * M * N * 4;
    } else {
        A = (const _Float16*)p.A[z]; W = (const _Float16*)p.W[z]; C = p.C[z];
        k0 = 0; k1 = K;
    }
    const int tid = threadIdx.x;
    const int m0 = blockIdx.x * 64, n0 = blockIdx.y * 64;
    const int srow = tid >> 2, skc = (tid & 3) * 8;
    const _Float16* Ald = A + (size_t)(m0 + srow) * K + k0 + skc;
    const _Float16* Wld = W + (size_t)(n0 + srow) * K + k0 + skc;
    const int wv = tid >> 6, lane = tid & 63;
    const int quad = lane >> 4, mr = lane & 15;

    f4v acc[4] = {};
    h8 aR = *(const h8*)Ald;
    h8 wR = *(const h8*)Wld;

    for (int kt = k0; kt < k1; kt += 32) {
        __syncthreads();
        *(h4*)&As[srow*40 + skc]     = __builtin_shufflevector(aR, aR, 0,1,2,3);
        *(h4*)&As[srow*40 + skc + 4] = __builtin_shufflevector(aR, aR, 4,5,6,7);
        *(h4*)&Ws[srow*40 + skc]     = __builtin_shufflevector(wR, wR, 0,1,2,3);
        *(h4*)&Ws[srow*40 + skc + 4] = __builtin_shufflevector(wR, wR, 4,5,6,7);
        __syncthreads();
        if (kt + 32 < k1) {
            Ald += 32; Wld += 32;
            aR = *(const h8*)Ald;
            wR = *(const h8*)Wld;
        }
        h8 af = ldsH8(&As[(wv*16 + mr)*40 + quad*8]);
        #pragma unroll
        for (int j = 0; j < 4; j++) {
            h8 bf = ldsH8(&Ws[(j*16 + mr)*40 + quad*8]);
            acc[j] = __builtin_amdgcn_mfma_f32_16x16x32_f16(af, bf, acc[j], 0, 0, 0);
        }
    }

    const int orow = m0 + wv*16 + quad*4;
    #pragma unroll
    for (int j = 0; j < 4; j++) {
        int col = n0 + j*16 + mr;
        #pragma unroll
        for (int rr = 0; rr < 4; rr++) {
            float v = acc[j][rr];
            if (RELU) v = fmaxf(v, 0.0f);
            if (OUTH) ((__half*)C)[(size_t)(orow + rr) * N + col] = __float2half(v);
            else      ((float*)C)[(size_t)(orow + rr) * N + col] = v;
        }
    }
}

// ---- split-K reduce + relu -> fp16 ----
__global__ __launch_bounds__(256) void reduce_relu_h_kernel(
    const float* __restrict__ pin, __half* __restrict__ hout)
{
    int i = blockIdx.x * 256 + threadIdx.x;
    const f4v* p4 = (const f4v*)pin;
    f4v a = p4[i];
    a += p4[i + MN/4];
    a += p4[i + 2*(MN/4)];
    a += p4[i + 3*(MN/4)];
    h4 o;
    #pragma unroll
    for (int j = 0; j < 4; j++) o[j] = (_Float16)fmaxf(a[j], 0.0f);
    *(h4*)(hout + (size_t)i*4) = o;
}

// ---- final heads (fp32 GEMV, one wave per roi) ----
__global__ __launch_bounds__(256) void heads_kernel(
    const float* __restrict__ c2, const float* __restrict__ i2, const float* __restrict__ r2,
    const float* __restrict__ wc3, const float* __restrict__ bc3,
    const float* __restrict__ wi3, const float* __restrict__ bi3,
    const float* __restrict__ wr3, const float* __restrict__ br3,
    float* __restrict__ out)
{
    const int lane = threadIdx.x & 63;
    const int wv   = threadIdx.x >> 6;
    const int n    = blockIdx.x * 4 + wv;
    const float* cr = c2 + (size_t)n*256;
    const float* ir = i2 + (size_t)n*256;
    const float* rr = r2 + (size_t)n*256;
    float vc = 0.0f, vi = 0.0f, vr[7] = {};
    #pragma unroll
    for (int j = 0; j < 4; j++) {
        int k = lane + j*64;
        float cv = cr[k], iv = ir[k], rv = rr[k];
        vc += cv * wc3[k];
        vi += iv * wi3[k];
        #pragma unroll
        for (int t = 0; t < 7; t++) vr[t] += rv * wr3[t*256 + k];
    }
    #pragma unroll
    for (int off = 32; off > 0; off >>= 1) {
        vc += __shfl_down(vc, off, 64);
        vi += __shfl_down(vi, off, 64);
        #pragma unroll
        for (int t = 0; t < 7; t++) vr[t] += __shfl_down(vr[t], off, 64);
    }
    if (lane == 0) {
        out[n]        = vc + bc3[0];
        out[2048 + n] = vi + bi3[0];
        #pragma unroll
        for (int t = 0; t < 7; t++) out[4096 + n*7 + t] = vr[t] + br3[t];
    }
}

extern "C" void kernel_launch(void* const* d_in, const int* in_sizes, int n_in,
                              void* d_out, int out_size, void* d_ws, size_t ws_size,
                              hipStream_t stream)
{
    const float* fm    = (const float*)d_in[0];
    const float* boxes = (const float*)d_in[1];
    const int*   bidx  = (const int*)d_in[2];
    const float* w_sh1 = (const float*)d_in[3];
    const float* w_sh2 = (const float*)d_in[4];
    const float* w_c1  = (const float*)d_in[5];
    const float* w_c2  = (const float*)d_in[6];
    const float* w_c3  = (const float*)d_in[7];
    const float* b_c3  = (const float*)d_in[8];
    const float* w_i1  = (const float*)d_in[9];
    const float* w_i2  = (const float*)d_in[10];
    const float* w_i3  = (const float*)d_in[11];
    const float* b_i3  = (const float*)d_in[12];
    const float* w_r1  = (const float*)d_in[13];
    const float* w_r2  = (const float*)d_in[14];
    const float* w_r3  = (const float*)d_in[15];
    const float* b_r3  = (const float*)d_in[16];
    float* out = (float*)d_out;

    // workspace layout (bytes)
    char* base = (char*)d_ws;
    __half* hwc  = (__half*)base;                                   // 128 MB
    __half* xh   = (__half*)(base + (size_t)4*NCH*HWSZ*2);          // 9 MB
    __half* h1h  = (__half*)((char*)xh + (size_t)NROI*FDIM*2);      // 1 MB
    __half* shh  = (__half*)((char*)h1h + (size_t)MN*2);            // 1 MB
    __half* b1c  = (__half*)((char*)shh + (size_t)MN*2);            // 3 MB
    __half* b1i  = b1c + MN;
    __half* b1r  = b1i + MN;
    float*  b2c  = (float*)((char*)b1c + (size_t)3*MN*2);           // 6 MB
    float*  b2i  = b2c + MN;
    float*  b2r  = b2i + MN;
    float*  part = (float*)((char*)b2c + (size_t)3*MN*4);           // 8 MB
    __half* wbuf = (__half*)((char*)part + (size_t)4*MN*4);         // 2 MB

    convert_w_kernel<<<2048, 256, 0, stream>>>(w_sh1, w_sh2, w_c1, w_c2,
                                               w_i1, w_i2, w_r1, w_r2, wbuf);
    transpose_kernel<<<dim3(2, 2, 4*MAPH), 256, 0, stream>>>(fm, hwc);
    roi_hwc_kernel<<<NROI/2, 256, 0, stream>>>(hwc, boxes, bidx, xh);

    PtrsH g1;
    g1.A[0]=g1.A[1]=g1.A[2]=xh;
    g1.W[0]=g1.W[1]=g1.W[2]=wbuf + O_SH1;
    g1.C[0]=g1.C[1]=g1.C[2]=part;
    gemm_h_kernel<false,true,false><<<dim3(32,4,4), 256, 0, stream>>>(g1, 2048, 256, 2304, 576);

    reduce_relu_h_kernel<<<MN/4/256, 256, 0, stream>>>(part, h1h);

    PtrsH g2;
    g2.A[0]=g2.A[1]=g2.A[2]=h1h;
    g2.W[0]=g2.W[1]=g2.W[2]=wbuf + O_SH2;
    g2.C[0]=g2.C[1]=g2.C[2]=shh;
    gemm_h_kernel<true,false,true><<<dim3(32,4,1), 256, 0, stream>>>(g2, 2048, 256, 256, 0);

    PtrsH g3;
    g3.A[0]=g3.A[1]=g3.A[2]=shh;
    g3.W[0]=wbuf + O_C1; g3.W[1]=wbuf + O_I1; g3.W[2]=wbuf + O_R1;
    g3.C[0]=b1c; g3.C[1]=b1i; g3.C[2]=b1r;
    gemm_h_kernel<true,false,true><<<dim3(32,4,3), 256, 0, stream>>>(g3, 2048, 256, 256, 0);

    PtrsH g4;
    g4.A[0]=b1c; g4.A[1]=b1i; g4.A[2]=b1r;
    g4.W[0]=wbuf + O_C2; g4.W[1]=wbuf + O_I2; g4.W[2]=wbuf + O_R2;
    g4.C[0]=b2c; g4.C[1]=b2i; g4.C[2]=b2r;
    gemm_h_kernel<true,false,false><<<dim3(32,4,3), 256, 0, stream>>>(g4, 2048, 256, 256, 0);

    heads_kernel<<<NROI/4, 256, 0, stream>>>(b2c, b2i, b2r,
                                             w_c3, b_c3, w_i3, b_i3, w_r3, b_r3, out);
}